// Round 2
// baseline (1135.598 us; speedup 1.0000x reference)
//
#include <hip/hip_runtime.h>
#include <cstddef>

#define Bz 4
#define Sz 1024
#define Dm 256
#define Hh 8
#define DHh 2048
#define SCALE 0.0625f

// ---------------- GEMM: C[M][N] = A[M][K] * W[K][N] + bias[N] ----------------
// 256 threads. Thread grid (BM/TM) x (BN/TN) must be 16x16.
template<int BM, int BN, int BK, int TM, int TN>
__global__ __launch_bounds__(256)
void gemm_bias(const float* __restrict__ A, const float* __restrict__ W,
               const float* __restrict__ bias, float* __restrict__ C,
               int M, int N, int K) {
  constexpr int TX = BN / TN;                 // 16
  __shared__ float As[BK][BM + 4];            // [k][m]
  __shared__ float Bs[BK][BN + 4];            // [k][n]
  const int tid = threadIdx.x;
  const int tc = tid % TX;
  const int tr = tid / TX;
  const int bm = blockIdx.y * BM;
  const int bn = blockIdx.x * BN;
  constexpr int AF4 = (BM * BK) / (4 * 256);
  constexpr int BF4 = (BN * BK) / (4 * 256);
  constexpr int NCH = TN / 4;                 // float4 column chunks per thread
  constexpr int CST = (NCH > 1) ? (BN / NCH) : 0;  // chunk stride (interleaved cols)

  float acc[TM][TN];
#pragma unroll
  for (int i = 0; i < TM; ++i)
#pragma unroll
    for (int j = 0; j < TN; ++j) acc[i][j] = 0.f;

  for (int kk = 0; kk < K; kk += BK) {
#pragma unroll
    for (int u = 0; u < AF4; ++u) {
      int idx = tid + u * 256;
      int r  = idx / (BK / 4);
      int k4 = (idx % (BK / 4)) * 4;
      float4 v = *(const float4*)&A[(size_t)(bm + r) * K + kk + k4];
      As[k4 + 0][r] = v.x; As[k4 + 1][r] = v.y;
      As[k4 + 2][r] = v.z; As[k4 + 3][r] = v.w;
    }
#pragma unroll
    for (int u = 0; u < BF4; ++u) {
      int idx = tid + u * 256;
      int r  = idx / (BN / 4);
      int c4 = (idx % (BN / 4)) * 4;
      *(float4*)&Bs[r][c4] = *(const float4*)&W[(size_t)(kk + r) * N + bn + c4];
    }
    __syncthreads();
#pragma unroll
    for (int k = 0; k < BK; ++k) {
      float a[TM], b[TN];
#pragma unroll
      for (int i = 0; i < TM; i += 4)
        *(float4*)&a[i] = *(const float4*)&As[k][tr * TM + i];
#pragma unroll
      for (int h = 0; h < NCH; ++h)
        *(float4*)&b[h * 4] = *(const float4*)&Bs[k][h * CST + tc * 4];
#pragma unroll
      for (int i = 0; i < TM; ++i)
#pragma unroll
        for (int j = 0; j < TN; ++j)
          acc[i][j] = fmaf(a[i], b[j], acc[i][j]);
    }
    __syncthreads();
  }
#pragma unroll
  for (int i = 0; i < TM; ++i) {
    int row = bm + tr * TM + i;
#pragma unroll
    for (int h = 0; h < NCH; ++h) {
      int col = bn + h * CST + tc * 4;
      float4 bv4 = *(const float4*)&bias[col];
      float4 o;
      o.x = acc[i][h * 4 + 0] + bv4.x;
      o.y = acc[i][h * 4 + 1] + bv4.y;
      o.z = acc[i][h * 4 + 2] + bv4.z;
      o.w = acc[i][h * 4 + 3] + bv4.w;
      *(float4*)&C[(size_t)row * N + col] = o;
    }
  }
}

// ---------------- Flash attention (fp32), softmax over the QUERY axis -------
// Reference: scores[b,h,kpos,qpos] = SCALE * <Kproj[b,kpos,h,:], Qproj[b,qpos,h,:]>
//            attn = softmax over qpos;  out[b,kpos,h,:] = sum_q attn * Vproj[b,q,h,:]
// => standard flash attention with flash-Q := Kproj, flash-K := Qproj.
#define ROWS 64
#define QT 32
#define QVS (Dm + 4)   // union-buffer row stride

__global__ __launch_bounds__(512)
void attn_flash(const float* __restrict__ Kp, const float* __restrict__ Qp,
                const float* __restrict__ Vp, float* __restrict__ Oc) {
  __shared__ float Ks[ROWS][Dm + 4];       // 64 x 260 fp32 (resident all loop)
  __shared__ float QVs[QT * QVS];          // union: Q rows [c][k] / V rows [c][d], both 32x260
  __shared__ float Ps[ROWS][QT + 4];       // score/prob tile

  const int tid = threadIdx.x;
  const int rb = blockIdx.x * ROWS;        // key-row block
  const int h  = blockIdx.y;
  const int b  = blockIdx.z;
  const size_t base = ((size_t)b * Sz) * DHh + (size_t)h * Dm;

  // stage K rows (attention's "Q"): row r = tid/8, 8 float4 at d = (tid&7)*4 + 32j
  {
    int r  = tid >> 3;
    int d0 = (tid & 7) * 4;
    const float* src = Kp + base + (size_t)(rb + r) * DHh;
#pragma unroll
    for (int j = 0; j < 8; ++j)
      *(float4*)&Ks[r][d0 + j * 32] = *(const float4*)&src[d0 + j * 32];
  }

  const int r_o = tid >> 3;            // output row owned by this thread (8 threads/row)
  const int dl  = (tid & 7) * 4;       // owned d-columns: dl + 32*j
  float4 o[8];
#pragma unroll
  for (int j = 0; j < 8; ++j) o[j] = make_float4(0.f, 0.f, 0.f, 0.f);
  float m_run = -3.0e38f, l_run = 0.f;

  // scores thread grid: 32x16, micro-tile split rows (r0, r0+32), cols (c0, c0+16)
  const int r0 = tid >> 4, c0 = tid & 15;
  const int r1 = r0 + 32,  c1 = c0 + 16;

  // staging coords shared by Q and V row copies (identical pattern)
  const int sc  = tid >> 4;            // row 0..31
  const int sd0 = (tid & 15) * 4;      // col chunk base

  for (int qt = 0; qt < Sz / QT; ++qt) {
    const int q0 = qt * QT;
    __syncthreads();                   // prev PV done with QVs (also fences K stage)

    // stage Q rows into union buffer: QVs[c][k], row-major
    {
      const float* src = Qp + base + (size_t)(q0 + sc) * DHh;
      float* dst = &QVs[sc * QVS];
#pragma unroll
      for (int j = 0; j < 4; ++j)
        *(float4*)&dst[sd0 + j * 64] = *(const float4*)&src[sd0 + j * 64];
    }
    __syncthreads();

    // scores: S[r][c] = <Ks[r], Q[c]>, 2x2 split micro-tile, all-b128 LDS reads
    {
      const float* kr0 = &Ks[r0][0];
      const float* kr1 = &Ks[r1][0];
      const float* qc0 = &QVs[c0 * QVS];
      const float* qc1 = &QVs[c1 * QVS];
      float s00 = 0.f, s01 = 0.f, s10 = 0.f, s11 = 0.f;
#pragma unroll 8
      for (int k4 = 0; k4 < Dm; k4 += 4) {
        float4 a0 = *(const float4*)&kr0[k4];
        float4 a1 = *(const float4*)&kr1[k4];
        float4 b0 = *(const float4*)&qc0[k4];
        float4 b1 = *(const float4*)&qc1[k4];
        s00 += a0.x * b0.x + a0.y * b0.y + a0.z * b0.z + a0.w * b0.w;
        s01 += a0.x * b1.x + a0.y * b1.y + a0.z * b1.z + a0.w * b1.w;
        s10 += a1.x * b0.x + a1.y * b0.y + a1.z * b0.z + a1.w * b0.w;
        s11 += a1.x * b1.x + a1.y * b1.y + a1.z * b1.z + a1.w * b1.w;
      }
      Ps[r0][c0] = s00 * SCALE;
      Ps[r0][c1] = s01 * SCALE;
      Ps[r1][c0] = s10 * SCALE;
      Ps[r1][c1] = s11 * SCALE;
    }
    __syncthreads();

    // stage V rows into union buffer (Q fully consumed): QVs[c][d]
    {
      const float* src = Vp + base + (size_t)(q0 + sc) * DHh;
      float* dst = &QVs[sc * QVS];
#pragma unroll
      for (int j = 0; j < 4; ++j)
        *(float4*)&dst[sd0 + j * 64] = *(const float4*)&src[sd0 + j * 64];
    }
    // online softmax over this tile's columns (8 threads per row)
    {
      const int cq = (tid & 7) * 4;
      float4 sv = *(const float4*)&Ps[r_o][cq];
      float tmax = fmaxf(fmaxf(sv.x, sv.y), fmaxf(sv.z, sv.w));
#pragma unroll
      for (int off = 1; off < 8; off <<= 1)
        tmax = fmaxf(tmax, __shfl_xor(tmax, off));
      float mnew  = fmaxf(m_run, tmax);
      float alpha = __expf(m_run - mnew);
      float4 p;
      p.x = __expf(sv.x - mnew); p.y = __expf(sv.y - mnew);
      p.z = __expf(sv.z - mnew); p.w = __expf(sv.w - mnew);
      float ps = p.x + p.y + p.z + p.w;
#pragma unroll
      for (int off = 1; off < 8; off <<= 1)
        ps += __shfl_xor(ps, off);
      l_run = l_run * alpha + ps;
      m_run = mnew;
      *(float4*)&Ps[r_o][cq] = p;
#pragma unroll
      for (int j = 0; j < 8; ++j) {
        o[j].x *= alpha; o[j].y *= alpha; o[j].z *= alpha; o[j].w *= alpha;
      }
    }
    __syncthreads();

    // PV: o[r_o][d] += P[r_o][c] * V[c][d]
    for (int c = 0; c < QT; ++c) {
      float p = Ps[r_o][c];
      const float* vrow = &QVs[c * QVS];
#pragma unroll
      for (int j = 0; j < 8; ++j) {
        float4 v = *(const float4*)&vrow[dl + j * 32];
        o[j].x = fmaf(p, v.x, o[j].x);
        o[j].y = fmaf(p, v.y, o[j].y);
        o[j].z = fmaf(p, v.z, o[j].z);
        o[j].w = fmaf(p, v.w, o[j].w);
      }
    }
  }

  // epilogue: normalize and write concat layout [b][s][h*Dm + d]
  {
    float inv = 1.0f / l_run;
    float* dst = Oc + ((size_t)b * Sz + rb + r_o) * DHh + (size_t)h * Dm;
#pragma unroll
    for (int j = 0; j < 8; ++j) {
      float4 v = o[j];
      v.x *= inv; v.y *= inv; v.z *= inv; v.w *= inv;
      *(float4*)&dst[dl + j * 32] = v;
    }
  }
}

extern "C" void kernel_launch(void* const* d_in, const int* in_sizes, int n_in,
                              void* d_out, int out_size, void* d_ws, size_t ws_size,
                              hipStream_t stream) {
  (void)in_sizes; (void)n_in; (void)out_size; (void)ws_size;
  const float* value_in = (const float*)d_in[0];
  const float* key_in   = (const float*)d_in[1];
  const float* query_in = (const float*)d_in[2];
  const float* Wv = (const float*)d_in[3];
  const float* bv = (const float*)d_in[4];
  const float* Wk = (const float*)d_in[5];
  const float* bk = (const float*)d_in[6];
  const float* Wq = (const float*)d_in[7];
  const float* bq = (const float*)d_in[8];
  const float* Wo = (const float*)d_in[9];
  const float* bo = (const float*)d_in[10];
  float* out = (float*)d_out;

  // ws layout (fp32): v | k | q | concat   — 4 x 33.55 MB = 134.2 MB
  float* vbuf = (float*)d_ws;
  float* kbuf = vbuf + (size_t)Bz * Sz * DHh;
  float* qbuf = kbuf + (size_t)Bz * Sz * DHh;
  float* obuf = qbuf + (size_t)Bz * Sz * DHh;

  dim3 gp(DHh / 128, (Bz * Sz) / 128);     // (16, 32)
  gemm_bias<128,128,16,8,8><<<gp, 256, 0, stream>>>(value_in, Wv, bv, vbuf, Bz*Sz, DHh, Dm);
  gemm_bias<128,128,16,8,8><<<gp, 256, 0, stream>>>(key_in,   Wk, bk, kbuf, Bz*Sz, DHh, Dm);
  gemm_bias<128,128,16,8,8><<<gp, 256, 0, stream>>>(query_in, Wq, bq, qbuf, Bz*Sz, DHh, Dm);

  dim3 ga(Sz / ROWS, Hh, Bz);              // (16, 8, 4)
  attn_flash<<<ga, 512, 0, stream>>>(kbuf, qbuf, vbuf, obuf);

  dim3 go(Dm / 64, (Bz * Sz) / 64);        // (4, 64)
  gemm_bias<64,64,16,4,4><<<go, 256, 0, stream>>>(obuf, Wo, bo, out, Bz*Sz, Dm, DHh);
}

// Round 3
// 251.321 us; speedup vs baseline: 4.5185x; 4.5185x over previous
//
#include <hip/hip_runtime.h>
#include <cstddef>
#include <cstdint>

#define Bz 4
#define Sz 1024
#define Dm 256
#define Hh 8
#define DHh 2048
#define SCALE 0.0625f

typedef __attribute__((ext_vector_type(8))) short short8;
typedef __attribute__((ext_vector_type(16))) float f32x16;

__device__ inline unsigned short f2bf(float f){
  unsigned u = __float_as_uint(f);
  u += 0x7FFFu + ((u >> 16) & 1u);           // round-to-nearest-even
  return (unsigned short)(u >> 16);
}
__device__ inline unsigned pk2(float a, float b){
  return (unsigned)f2bf(a) | ((unsigned)f2bf(b) << 16);
}
__device__ inline void gll16(const void* g, void* l){
  __builtin_amdgcn_global_load_lds((const __attribute__((address_space(1))) unsigned*)g,
                                   (__attribute__((address_space(3))) unsigned*)l, 16, 0, 0);
}
__device__ inline short8 lds8(const char* p){ return *(const short8*)p; }
__device__ inline f32x16 MM(short8 a, short8 b, f32x16 c){
  return __builtin_amdgcn_mfma_f32_32x32x16_bf16(a, b, c, 0, 0, 0);
}
__device__ inline f32x16 z16(){ f32x16 v; 
#pragma unroll
  for(int i=0;i<16;i++) v[i]=0.f; return v; }

// ---------------- fp32 -> bf16 convert ----------------
__global__ __launch_bounds__(256) void cvt_bf16(const float* __restrict__ src,
                                                unsigned short* __restrict__ dst, int n4){
  int i = blockIdx.x*256 + threadIdx.x;
  if(i < n4){
    float4 v = ((const float4*)src)[i];
    ushort4 o; o.x=f2bf(v.x); o.y=f2bf(v.y); o.z=f2bf(v.z); o.w=f2bf(v.w);
    ((ushort4*)dst)[i] = o;
  }
}

// ---------------- W [K][N] fp32 -> Wt [N][K] bf16 ----------------
__global__ __launch_bounds__(256) void cvt_transpose(const float* __restrict__ W,
    unsigned short* __restrict__ Wt, int K, int N){
  __shared__ float t[32][33];
  const int n0 = blockIdx.x*32, k0 = blockIdx.y*32;
  const int a = threadIdx.x >> 5, c = threadIdx.x & 31;
#pragma unroll
  for(int p=0;p<4;p++)
    t[a + p*8][c] = W[(size_t)(k0 + a + p*8)*N + n0 + c];
  __syncthreads();
#pragma unroll
  for(int p=0;p<4;p++)
    Wt[(size_t)(n0 + a + p*8)*K + k0 + c] = f2bf(t[c][a + p*8]);
}

// ---------------- projection GEMM: C[4096 x 2048] = A[4096x256] @ W + bias ----
// A bf16 [M][256]; Bt bf16 [2048][256] (= W^T). Tile 128x128, BK=64, 4 warps.
// VAR: 0 plain bf16 out, 1 (x SCALE) bf16 out (K), 2 transposed Vt[b][h][d][s] out (V)
template<int VAR>
__global__ __launch_bounds__(256) void gemm_proj(const unsigned short* __restrict__ A,
    const unsigned short* __restrict__ Bt, const float* __restrict__ bias,
    unsigned short* __restrict__ C){
  __shared__ __align__(16) char sm[32768];
  const int tid = threadIdx.x, w = tid>>6, lane = tid&63, l31 = lane&31, hp = lane>>5;
  const int wm = (w>>1)*64, wn = (w&1)*64;
  const int bm = blockIdx.y*128, bn = blockIdx.x*128;
  f32x16 acc[2][2]; acc[0][0]=z16(); acc[0][1]=z16(); acc[1][0]=z16(); acc[1][1]=z16();
  for(int kk=0; kk<256; kk+=64){
#pragma unroll
    for(int j=0;j<4;j++){
      int ci = (w*4+j)*64 + lane;          // 0..1023
      int m = ci>>3, sl = ci&7;
      gll16(A  + (size_t)(bm+m)*256 + kk + ((sl ^ (m&7))<<3), sm + (w*4+j)*1024);
      gll16(Bt + (size_t)(bn+m)*256 + kk + ((sl ^ (m&7))<<3), sm + 16384 + (w*4+j)*1024);
    }
    __syncthreads();
#pragma unroll
    for(int s=0;s<4;s++){
      int m0 = wm + l31, m1 = wm + 32 + l31;
      int n0 = wn + l31, n1 = wn + 32 + l31;
      short8 a0 = lds8(sm + m0*128 + (((s*2+hp) ^ (m0&7))<<4));
      short8 a1 = lds8(sm + m1*128 + (((s*2+hp) ^ (m1&7))<<4));
      short8 b0 = lds8(sm + 16384 + n0*128 + (((s*2+hp) ^ (n0&7))<<4));
      short8 b1 = lds8(sm + 16384 + n1*128 + (((s*2+hp) ^ (n1&7))<<4));
      acc[0][0] = MM(a0,b0,acc[0][0]); acc[0][1] = MM(a0,b1,acc[0][1]);
      acc[1][0] = MM(a1,b0,acc[1][0]); acc[1][1] = MM(a1,b1,acc[1][1]);
    }
    __syncthreads();
  }
#pragma unroll
  for(int nh=0; nh<2; nh++){
    int ncol = bn + wn + nh*32 + l31;
    float bb = bias[ncol];
#pragma unroll
    for(int mh=0; mh<2; mh++){
      if(VAR == 2){
        int hidx = ncol >> 8, d = ncol & 255;
#pragma unroll
        for(int g=0; g<4; g++){
          int mrow = bm + wm + mh*32 + 8*g + 4*hp;
          int batch = mrow >> 10, sin = mrow & 1023;
          unsigned u0 = pk2(acc[mh][nh][4*g+0] + bb, acc[mh][nh][4*g+1] + bb);
          unsigned u1 = pk2(acc[mh][nh][4*g+2] + bb, acc[mh][nh][4*g+3] + bb);
          uint2 uu; uu.x = u0; uu.y = u1;
          *(uint2*)(C + ((size_t)((batch*Hh + hidx)*Dm + d))*Sz + sin) = uu;
        }
      } else {
#pragma unroll
        for(int r=0; r<16; r++){
          int mrow = bm + wm + mh*32 + (r&3) + 8*(r>>2) + 4*hp;
          float v = acc[mh][nh][r] + bb;
          if(VAR == 1) v *= SCALE;
          C[(size_t)mrow*DHh + ncol] = f2bf(v);
        }
      }
    }
  }
}

// ---------------- flash attention (bf16 MFMA) -------------------------------
// S[r][c] = <Kp[r]*SCALE, Qp[c]> (SCALE pre-folded into Kp), softmax over c,
// O[r][d] = sum_c P V[c][d].  Swapped QK^T: T[c][r] = mfma(A=Qp, B=Kp) so each
// lane owns row r = lane&31 stats lane-locally.
// 8 warps: rg = w&3 (32 rows each, block = 128 rows), set = w>>2 (KV half).
__global__ __launch_bounds__(512, 2) void attn_mfma(
    const unsigned short* __restrict__ Kp, const unsigned short* __restrict__ Qp,
    const unsigned short* __restrict__ Vt, unsigned short* __restrict__ Oc){
  __shared__ __align__(16) char sm[133120];
  // loop phase:  [0,16K) QpA | [16K,32K) QpB | [32K,48K) VtA | [48K,64K) VtB
  // merge phase: [0,128K) = [4 rg][32 r][256 d] f32 ; stats f32[8][32][2] at 128K
  const int tid = threadIdx.x, w = tid>>6, lane = tid&63, l31 = lane&31, hp = lane>>5;
  const int set = w>>2, ws = w&3;
  const int h = blockIdx.y, b = blockIdx.z;
  const int brow0 = blockIdx.x*128;
  const size_t vtbase = ((size_t)((b*Hh + h)*Dm))*Sz;

  // K rows of this row-group, as B-op fragments (col=lane&31=r, k=(lane>>5)*8+j)
  short8 kp[16];
  {
    const unsigned short* kr = Kp + (size_t)(b*Sz + brow0 + ws*32 + l31)*DHh + h*Dm + hp*8;
#pragma unroll
    for(int ki=0; ki<16; ki++) kp[ki] = *(const short8*)(kr + ki*16);
  }
  f32x16 acc[8];
#pragma unroll
  for(int f=0; f<8; f++) acc[f] = z16();
  float m_run = -3.0e38f, l_run = 0.f;
  char* qpL = sm + set*16384;
  char* vtL = sm + 32768 + set*16384;

  for(int it=0; it<16; ++it){
    const int kv0 = set*512 + it*32;
    // stage Qp [32c][256k] (slot^(c&31)) and Vt [128dp][2d x 32c] (slot^(dp&7))
#pragma unroll
    for(int j=0; j<4; j++){
      int ci = (ws*4+j)*64 + lane;         // 0..1023
      int c = ci>>5, sl5 = ci&31;
      gll16(Qp + (size_t)(b*Sz + kv0 + c)*DHh + h*Dm + ((sl5 ^ (c&31))<<3),
            qpL + (ws*4+j)*1024);
      int dp = ci>>3, sv = (ci&7) ^ (dp&7);
      int d = dp*2 + (sv>>2), co = (sv&3)*8;
      gll16(Vt + vtbase + (size_t)d*Sz + kv0 + co, vtL + (ws*4+j)*1024);
    }
    __syncthreads();
    // QK^T: T[32c][32r], A = Qp frags, B = kp regs
    f32x16 S = z16();
#pragma unroll
    for(int ki=0; ki<16; ki++){
      short8 a = lds8(qpL + l31*512 + (((ki*2+hp) ^ (l31&31))<<4));
      S = MM(a, kp[ki], S);
    }
    // online softmax, lane-local for r = l31 (c-halves joined via shfl_xor 32)
    float tmax = S[0];
#pragma unroll
    for(int r=1; r<16; r++) tmax = fmaxf(tmax, S[r]);
    tmax = fmaxf(tmax, __shfl_xor(tmax, 32));
    if(!__all(tmax <= m_run + 8.0f)){
      float mnew = fmaxf(m_run, tmax);
      float alpha = __expf(m_run - mnew);
      m_run = mnew; l_run *= alpha;
#pragma unroll
      for(int r=0; r<16; r++){
        int rr = (r&3) + 8*(r>>2) + 4*hp;
        float ar = __shfl(alpha, rr);
#pragma unroll
        for(int f=0; f<8; f++) acc[f][r] *= ar;
      }
    }
    float lsum = 0.f;
#pragma unroll
    for(int r=0; r<16; r++){ S[r] = __expf(S[r] - m_run); lsum += S[r]; }
    lsum += __shfl_xor(lsum, 32);
    l_run += lsum;
    // pack P -> bf16 A-op frags (row=lane&31=r, k=c), halves joined via shfl
    short8 pa[2];
#pragma unroll
    for(int t=0; t<2; t++){
      unsigned w01 = pk2(S[t*8+0], S[t*8+1]);
      unsigned w23 = pk2(S[t*8+2], S[t*8+3]);
      unsigned w45 = pk2(S[t*8+4], S[t*8+5]);
      unsigned w67 = pk2(S[t*8+6], S[t*8+7]);
      unsigned x01 = __shfl_xor(w01, 32), x23 = __shfl_xor(w23, 32);
      unsigned x45 = __shfl_xor(w45, 32), x67 = __shfl_xor(w67, 32);
      union { unsigned u[4]; short8 s8; } U;
      if(hp == 0){ U.u[0]=w01; U.u[1]=w23; U.u[2]=x01; U.u[3]=x23; }
      else       { U.u[0]=x45; U.u[1]=x67; U.u[2]=w45; U.u[3]=w67; }
      pa[t] = U.s8;
    }
    // PV: acc[f] += P[32r x 16c] @ V[16c x 32d]
#pragma unroll
    for(int t=0; t<2; t++){
#pragma unroll
      for(int f=0; f<8; f++){
        int d = f*32 + l31;
        int dp = d>>1;
        int slot = (d&1)*4 + t*2 + hp;
        short8 vfr = lds8(vtL + dp*128 + ((slot ^ (dp&7))<<4));
        acc[f] = MM(pa[t], vfr, acc[f]);
      }
    }
    __syncthreads();
  }
  // ---- merge the two KV halves, then store bf16 concat ----
  float* stats = (float*)(sm + 131072);
  if(lane < 32){ stats[(w*32 + lane)*2 + 0] = m_run; stats[(w*32 + lane)*2 + 1] = l_run; }
  __syncthreads();
  float* mg = (float*)sm + ws*8192;        // [32 r][256 d] f32 for this rg
  if(set == 1){
    float mA = stats[(ws*32 + l31)*2 + 0];
    float mf = fmaxf(mA, m_run);
    float bB = __expf(m_run - mf);
#pragma unroll
    for(int r=0; r<16; r++){
      int rr = (r&3) + 8*(r>>2) + 4*hp;
      float br = __shfl(bB, rr);
#pragma unroll
      for(int f=0; f<8; f++) mg[rr*256 + f*32 + l31] = acc[f][r]*br;
    }
  }
  __syncthreads();
  if(set == 0){
    float mB = stats[((4+ws)*32 + l31)*2 + 0];
    float lB = stats[((4+ws)*32 + l31)*2 + 1];
    float mf = fmaxf(m_run, mB);
    float bA = __expf(m_run - mf), bBv = __expf(mB - mf);
    float inv = 1.0f / (l_run*bA + lB*bBv);
#pragma unroll
    for(int r=0; r<16; r++){
      int rr = (r&3) + 8*(r>>2) + 4*hp;
      float bAr = __shfl(bA, rr);
      float invr = __shfl(inv, rr);
      int srow = brow0 + ws*32 + rr;
#pragma unroll
      for(int f=0; f<8; f++){
        float v = (acc[f][r]*bAr + mg[rr*256 + f*32 + l31]) * invr;
        Oc[(size_t)(b*Sz + srow)*DHh + h*Dm + f*32 + l31] = f2bf(v);
      }
    }
  }
}

// ---------------- output GEMM: out[4096x256] = concat[4096x2048] @ Wo + bo ---
// concat bf16, Wot bf16 [256][2048]; 1 warp per block, 32x32 tile, BK=64.
__global__ __launch_bounds__(64) void gemm_out(const unsigned short* __restrict__ A,
    const unsigned short* __restrict__ Bt, const float* __restrict__ bias,
    float* __restrict__ C){
  __shared__ __align__(16) char sm[8192];
  const int lane = threadIdx.x, l31 = lane&31, hp = lane>>5;
  const int bm = blockIdx.y*32, bn = blockIdx.x*32;
  f32x16 acc = z16();
  for(int kk=0; kk<2048; kk+=64){
#pragma unroll
    for(int j=0; j<4; j++){
      int ci = j*64 + lane;                // 0..255
      int m = ci>>3, sl = ci&7;
      gll16(A  + (size_t)(bm+m)*DHh + kk + ((sl ^ (m&7))<<3), sm + j*1024);
      gll16(Bt + (size_t)(bn+m)*DHh + kk + ((sl ^ (m&7))<<3), sm + 4096 + j*1024);
    }
    __syncthreads();
#pragma unroll
    for(int s=0; s<4; s++){
      short8 a = lds8(sm + l31*128 + (((s*2+hp) ^ (l31&7))<<4));
      short8 b = lds8(sm + 4096 + l31*128 + (((s*2+hp) ^ (l31&7))<<4));
      acc = MM(a, b, acc);
    }
    __syncthreads();
  }
  float bb = bias[bn + l31];
#pragma unroll
  for(int r=0; r<16; r++){
    int mrow = bm + (r&3) + 8*(r>>2) + 4*hp;
    C[(size_t)mrow*Dm + bn + l31] = acc[r] + bb;
  }
}

extern "C" void kernel_launch(void* const* d_in, const int* in_sizes, int n_in,
                              void* d_out, int out_size, void* d_ws, size_t ws_size,
                              hipStream_t stream){
  (void)in_sizes; (void)n_in; (void)out_size; (void)ws_size;
  const float* value_in = (const float*)d_in[0];
  const float* key_in   = (const float*)d_in[1];
  const float* query_in = (const float*)d_in[2];
  const float* Wv = (const float*)d_in[3];
  const float* bv = (const float*)d_in[4];
  const float* Wk = (const float*)d_in[5];
  const float* bk = (const float*)d_in[6];
  const float* Wq = (const float*)d_in[7];
  const float* bq = (const float*)d_in[8];
  const float* Wo = (const float*)d_in[9];
  const float* bo = (const float*)d_in[10];

  char* ws = (char*)d_ws;
  unsigned short* av  = (unsigned short*)(ws + ((size_t) 0u<<20));  // 2MB
  unsigned short* ak  = (unsigned short*)(ws + ((size_t) 2u<<20));  // 2MB
  unsigned short* aq  = (unsigned short*)(ws + ((size_t) 4u<<20));  // 2MB
  unsigned short* wtv = (unsigned short*)(ws + ((size_t) 6u<<20));  // 1MB
  unsigned short* wtk = (unsigned short*)(ws + ((size_t) 7u<<20));  // 1MB
  unsigned short* wtq = (unsigned short*)(ws + ((size_t) 8u<<20));  // 1MB
  unsigned short* wto = (unsigned short*)(ws + ((size_t) 9u<<20));  // 1MB
  unsigned short* vt  = (unsigned short*)(ws + ((size_t)10u<<20));  // 16MB [b][h][d][s]
  unsigned short* kb  = (unsigned short*)(ws + ((size_t)26u<<20));  // 16MB (pre-scaled)
  unsigned short* qb  = (unsigned short*)(ws + ((size_t)42u<<20));  // 16MB
  unsigned short* cc  = (unsigned short*)(ws + ((size_t)58u<<20));  // 16MB concat

  cvt_bf16<<<1024, 256, 0, stream>>>(value_in, av, 262144);
  cvt_bf16<<<1024, 256, 0, stream>>>(key_in,   ak, 262144);
  cvt_bf16<<<1024, 256, 0, stream>>>(query_in, aq, 262144);
  cvt_transpose<<<dim3(64, 8), 256, 0, stream>>>(Wv, wtv, 256, 2048);
  cvt_transpose<<<dim3(64, 8), 256, 0, stream>>>(Wk, wtk, 256, 2048);
  cvt_transpose<<<dim3(64, 8), 256, 0, stream>>>(Wq, wtq, 256, 2048);
  cvt_transpose<<<dim3(8, 64), 256, 0, stream>>>(Wo, wto, 2048, 256);

  gemm_proj<2><<<dim3(16, 32), 256, 0, stream>>>(av, wtv, bv, vt);
  gemm_proj<1><<<dim3(16, 32), 256, 0, stream>>>(ak, wtk, bk, kb);
  gemm_proj<0><<<dim3(16, 32), 256, 0, stream>>>(aq, wtq, bq, qb);

  attn_mfma<<<dim3(8, Hh, Bz), 512, 0, stream>>>(kb, qb, vt, cc);

  gemm_out<<<dim3(8, 128), 64, 0, stream>>>(cc, wto, bo, (float*)d_out);
}

// Round 4
// 208.155 us; speedup vs baseline: 5.4555x; 1.2074x over previous
//
#include <hip/hip_runtime.h>
#include <cstddef>
#include <cstdint>

#define Bz 4
#define Sz 1024
#define Dm 256
#define Hh 8
#define DHh 2048
#define SCALE 0.0625f

typedef __attribute__((ext_vector_type(8))) short short8;
typedef __attribute__((ext_vector_type(16))) float f32x16;

__device__ inline unsigned short f2bf(float f){
  unsigned u = __float_as_uint(f);
  u += 0x7FFFu + ((u >> 16) & 1u);           // round-to-nearest-even
  return (unsigned short)(u >> 16);
}
__device__ inline unsigned pk2(float a, float b){
  return (unsigned)f2bf(a) | ((unsigned)f2bf(b) << 16);
}
__device__ inline void gll16(const void* g, void* l){
  __builtin_amdgcn_global_load_lds((const __attribute__((address_space(1))) unsigned*)g,
                                   (__attribute__((address_space(3))) unsigned*)l, 16, 0, 0);
}
__device__ inline short8 lds8(const char* p){ return *(const short8*)p; }
__device__ inline f32x16 MM(short8 a, short8 b, f32x16 c){
  return __builtin_amdgcn_mfma_f32_32x32x16_bf16(a, b, c, 0, 0, 0);
}
__device__ inline f32x16 z16(){ f32x16 v;
#pragma unroll
  for(int i=0;i<16;i++) v[i]=0.f; return v; }

// ---------------- fused fp32 -> bf16 convert (3 activations) ----------------
__global__ __launch_bounds__(256) void cvt_a(
    const float* __restrict__ S0, const float* __restrict__ S1, const float* __restrict__ S2,
    unsigned short* __restrict__ D0, unsigned short* __restrict__ D1, unsigned short* __restrict__ D2){
  const int bx = blockIdx.x;                 // 0..3071
  const int seg = bx >> 10;
  const float* src = seg==0 ? S0 : seg==1 ? S1 : S2;
  unsigned short* dst = seg==0 ? D0 : seg==1 ? D1 : D2;
  const int i = (bx & 1023)*256 + threadIdx.x;
  float4 v = ((const float4*)src)[i];
  ushort4 o; o.x=f2bf(v.x); o.y=f2bf(v.y); o.z=f2bf(v.z); o.w=f2bf(v.w);
  ((ushort4*)dst)[i] = o;
}

// ---------------- fused W [K][N] fp32 -> Wt [N][K] bf16 (4 weights) ---------
__global__ __launch_bounds__(256) void cvt_w(
    const float* __restrict__ W0, const float* __restrict__ W1,
    const float* __restrict__ W2, const float* __restrict__ W3,
    unsigned short* __restrict__ T0, unsigned short* __restrict__ T1,
    unsigned short* __restrict__ T2, unsigned short* __restrict__ T3){
  __shared__ float t[32][33];
  const int z = blockIdx.z;
  const float* W = z==0 ? W0 : z==1 ? W1 : z==2 ? W2 : W3;
  unsigned short* T = z==0 ? T0 : z==1 ? T1 : z==2 ? T2 : T3;
  const int K = (z<3) ? 256 : 2048;
  const int N = (z<3) ? 2048 : 256;
  const int n0 = (z<3) ? blockIdx.x*32 : blockIdx.y*32;
  const int k0 = (z<3) ? blockIdx.y*32 : blockIdx.x*32;
  const int a = threadIdx.x >> 5, c = threadIdx.x & 31;
#pragma unroll
  for(int p=0;p<4;p++)
    t[a + p*8][c] = W[(size_t)(k0 + a + p*8)*N + n0 + c];
  __syncthreads();
#pragma unroll
  for(int p=0;p<4;p++)
    T[(size_t)(n0 + a + p*8)*K + k0 + c] = f2bf(t[c][a + p*8]);
}

// ---------------- projection GEMM: C[4096 x 2048] = A[4096x256] @ W + bias ----
// A bf16 [M][256]; Bt bf16 [2048][256] (= W^T). Tile 128x128, BK=64, 4 warps,
// double-buffered staging (1 barrier / K-step).
// VAR: 0 plain bf16 out, 1 (x SCALE) bf16 out (K), 2 transposed Vt[b][h][d][s] out (V)
template<int VAR>
__global__ __launch_bounds__(256) void gemm_proj(const unsigned short* __restrict__ A,
    const unsigned short* __restrict__ Bt, const float* __restrict__ bias,
    unsigned short* __restrict__ C){
  __shared__ __align__(16) char sm[65536];   // [db][A 16K | B 16K]
  const int tid = threadIdx.x, w = tid>>6, lane = tid&63, l31 = lane&31, hp = lane>>5;
  const int wm = (w>>1)*64, wn = (w&1)*64;
  const int bm = blockIdx.y*128, bn = blockIdx.x*128;
  f32x16 acc[2][2]; acc[0][0]=z16(); acc[0][1]=z16(); acc[1][0]=z16(); acc[1][1]=z16();

  auto STAGE = [&](int db, int kk){
#pragma unroll
    for(int j=0;j<4;j++){
      int ci = (w*4+j)*64 + lane;          // 0..1023
      int m = ci>>3, sl = ci&7;
      gll16(A  + (size_t)(bm+m)*256 + kk + ((sl ^ (m&7))<<3), sm + db*32768 + (w*4+j)*1024);
      gll16(Bt + (size_t)(bn+m)*256 + kk + ((sl ^ (m&7))<<3), sm + db*32768 + 16384 + (w*4+j)*1024);
    }
  };

  STAGE(0, 0);
  __syncthreads();
  int db = 0;
  for(int t=0; t<4; ++t){
    if(t<3) STAGE(db^1, (t+1)*64);
    const char* base = sm + db*32768;
#pragma unroll
    for(int s=0;s<4;s++){
      int m0 = wm + l31, m1 = wm + 32 + l31;
      int n0 = wn + l31, n1 = wn + 32 + l31;
      short8 a0 = lds8(base + m0*128 + (((s*2+hp) ^ (m0&7))<<4));
      short8 a1 = lds8(base + m1*128 + (((s*2+hp) ^ (m1&7))<<4));
      short8 b0 = lds8(base + 16384 + n0*128 + (((s*2+hp) ^ (n0&7))<<4));
      short8 b1 = lds8(base + 16384 + n1*128 + (((s*2+hp) ^ (n1&7))<<4));
      acc[0][0] = MM(a0,b0,acc[0][0]); acc[0][1] = MM(a0,b1,acc[0][1]);
      acc[1][0] = MM(a1,b0,acc[1][0]); acc[1][1] = MM(a1,b1,acc[1][1]);
    }
    __syncthreads();
    db ^= 1;
  }
#pragma unroll
  for(int nh=0; nh<2; nh++){
    int ncol = bn + wn + nh*32 + l31;
    float bb = bias[ncol];
#pragma unroll
    for(int mh=0; mh<2; mh++){
      if(VAR == 2){
        int hidx = ncol >> 8, d = ncol & 255;
#pragma unroll
        for(int g=0; g<4; g++){
          int mrow = bm + wm + mh*32 + 8*g + 4*hp;
          int batch = mrow >> 10, sin = mrow & 1023;
          unsigned u0 = pk2(acc[mh][nh][4*g+0] + bb, acc[mh][nh][4*g+1] + bb);
          unsigned u1 = pk2(acc[mh][nh][4*g+2] + bb, acc[mh][nh][4*g+3] + bb);
          uint2 uu; uu.x = u0; uu.y = u1;
          *(uint2*)(C + ((size_t)((batch*Hh + hidx)*Dm + d))*Sz + sin) = uu;
        }
      } else {
#pragma unroll
        for(int r=0; r<16; r++){
          int mrow = bm + wm + mh*32 + (r&3) + 8*(r>>2) + 4*hp;
          float v = acc[mh][nh][r] + bb;
          if(VAR == 1) v *= SCALE;
          C[(size_t)mrow*DHh + ncol] = f2bf(v);
        }
      }
    }
  }
}

// ---------------- flash attention (bf16 MFMA) -------------------------------
// S[r][c] = <Kp[r]*SCALE, Qp[c]> (SCALE pre-folded into Kp), softmax over c,
// O[r][d] = sum_c P V[c][d].  Swapped QK^T: T[c][r] = mfma(A=Qp, B=Kp) so each
// lane owns row r = lane&31 stats lane-locally.
// 8 warps: rg = w&3 (32 rows each, block = 128 rows), set = w>>2 (KV half).
// XCD-swizzled 1-D grid (256): all 8 row-blocks of one (b,h) on one XCD -> L2 reuse.
// Double-buffered Q/V staging: 1 barrier per KV tile, loads hidden under compute.
__global__ __launch_bounds__(512, 2) void attn_mfma(
    const unsigned short* __restrict__ Kp, const unsigned short* __restrict__ Qp,
    const unsigned short* __restrict__ Vt, unsigned short* __restrict__ Oc){
  __shared__ __align__(16) char sm[133120];
  // loop phase:  [db*64K + set*16K) Qp | [db*64K + 32K + set*16K) Vt, db in {0,1}
  // merge phase: [0,128K) = [4 rg][32 r][256 d] f32 ; stats f32[8][32][2] at 128K
  const int tid = threadIdx.x, w = tid>>6, lane = tid&63, l31 = lane&31, hp = lane>>5;
  const int set = w>>2, ws = w&3;
  // XCD-aware decode: xcd = bid&7 owns (b,h) groups 4*xcd .. 4*xcd+3
  const int bid = blockIdx.x;
  const int g = (bid & 7)*4 + (bid >> 6);
  const int b = g >> 3, h = g & 7;
  const int brow0 = ((bid >> 3) & 7) * 128;
  const size_t vtbase = ((size_t)((b*Hh + h)*Dm))*Sz;

  // K rows of this row-group, as B-op fragments (col=lane&31=r, k=(lane>>5)*8+j)
  short8 kp[16];
  {
    const unsigned short* kr = Kp + (size_t)(b*Sz + brow0 + ws*32 + l31)*DHh + h*Dm + hp*8;
#pragma unroll
    for(int ki=0; ki<16; ki++) kp[ki] = *(const short8*)(kr + ki*16);
  }
  f32x16 acc[8];
#pragma unroll
  for(int f=0; f<8; f++) acc[f] = z16();
  float m_run = -3.0e38f, l_run = 0.f;

  auto STAGE = [&](int db, int it){
    const int kv0 = set*512 + it*32;
    char* qpD = sm + db*65536 + set*16384;
    char* vtD = sm + db*65536 + 32768 + set*16384;
#pragma unroll
    for(int j=0; j<4; j++){
      int ci = (ws*4+j)*64 + lane;         // 0..1023
      int c = ci>>5, sl5 = ci&31;
      gll16(Qp + (size_t)(b*Sz + kv0 + c)*DHh + h*Dm + ((sl5 ^ c)<<3),
            qpD + (ws*4+j)*1024);
      int dp = ci>>3, sv = (ci&7) ^ (dp&7);
      int d = dp*2 + (sv>>2), co = (sv&3)*8;
      gll16(Vt + vtbase + (size_t)d*Sz + kv0 + co, vtD + (ws*4+j)*1024);
    }
  };

  STAGE(0, 0);
  __syncthreads();
  int db = 0;
  for(int it=0; it<16; ++it){
    if(it<15) STAGE(db^1, it+1);         // prefetch next tile; drained by barrier below
    const char* qpL = sm + db*65536 + set*16384;
    const char* vtL = sm + db*65536 + 32768 + set*16384;
    // QK^T: T[32c][32r], A = Qp frags, B = kp regs
    f32x16 S = z16();
#pragma unroll
    for(int ki=0; ki<16; ki++){
      short8 a = lds8(qpL + l31*512 + (((ki*2+hp) ^ l31)<<4));
      S = MM(a, kp[ki], S);
    }
    // online softmax, lane-local for r = l31 (c-halves joined via shfl_xor 32)
    float tmax = S[0];
#pragma unroll
    for(int r=1; r<16; r++) tmax = fmaxf(tmax, S[r]);
    tmax = fmaxf(tmax, __shfl_xor(tmax, 32));
    if(!__all(tmax <= m_run + 8.0f)){
      float mnew = fmaxf(m_run, tmax);
      float alpha = __expf(m_run - mnew);
      m_run = mnew; l_run *= alpha;
#pragma unroll
      for(int r=0; r<16; r++){
        int rr = (r&3) + 8*(r>>2) + 4*hp;
        float ar = __shfl(alpha, rr);
#pragma unroll
        for(int f=0; f<8; f++) acc[f][r] *= ar;
      }
    }
    float lsum = 0.f;
#pragma unroll
    for(int r=0; r<16; r++){ S[r] = __expf(S[r] - m_run); lsum += S[r]; }
    lsum += __shfl_xor(lsum, 32);
    l_run += lsum;
    // pack P -> bf16 A-op frags (row=lane&31=r, k=c), halves joined via shfl
    short8 pa[2];
#pragma unroll
    for(int t=0; t<2; t++){
      unsigned w01 = pk2(S[t*8+0], S[t*8+1]);
      unsigned w23 = pk2(S[t*8+2], S[t*8+3]);
      unsigned w45 = pk2(S[t*8+4], S[t*8+5]);
      unsigned w67 = pk2(S[t*8+6], S[t*8+7]);
      unsigned x01 = __shfl_xor(w01, 32), x23 = __shfl_xor(w23, 32);
      unsigned x45 = __shfl_xor(w45, 32), x67 = __shfl_xor(w67, 32);
      union { unsigned u[4]; short8 s8; } U;
      if(hp == 0){ U.u[0]=w01; U.u[1]=w23; U.u[2]=x01; U.u[3]=x23; }
      else       { U.u[0]=x45; U.u[1]=x67; U.u[2]=w45; U.u[3]=w67; }
      pa[t] = U.s8;
    }
    // PV: acc[f] += P[32r x 16c] @ V[16c x 32d]
#pragma unroll
    for(int t=0; t<2; t++){
#pragma unroll
      for(int f=0; f<8; f++){
        int d = f*32 + l31;
        int dp = d>>1;
        int slot = (d&1)*4 + t*2 + hp;
        short8 vfr = lds8(vtL + dp*128 + ((slot ^ (dp&7))<<4));
        acc[f] = MM(pa[t], vfr, acc[f]);
      }
    }
    __syncthreads();                     // drains prefetch vmcnt + guards buffer swap
    db ^= 1;
  }
  // ---- merge the two KV halves, then store bf16 concat ----
  float* stats = (float*)(sm + 131072);
  if(lane < 32){ stats[(w*32 + lane)*2 + 0] = m_run; stats[(w*32 + lane)*2 + 1] = l_run; }
  __syncthreads();
  float* mg = (float*)sm + ws*8192;        // [32 r][256 d] f32 for this rg
  if(set == 1){
    float mA = stats[(ws*32 + l31)*2 + 0];
    float mf = fmaxf(mA, m_run);
    float bB = __expf(m_run - mf);
#pragma unroll
    for(int r=0; r<16; r++){
      int rr = (r&3) + 8*(r>>2) + 4*hp;
      float br = __shfl(bB, rr);
#pragma unroll
      for(int f=0; f<8; f++) mg[rr*256 + f*32 + l31] = acc[f][r]*br;
    }
  }
  __syncthreads();
  if(set == 0){
    float mB = stats[((4+ws)*32 + l31)*2 + 0];
    float lB = stats[((4+ws)*32 + l31)*2 + 1];
    float mf = fmaxf(m_run, mB);
    float bA = __expf(m_run - mf), bBv = __expf(mB - mf);
    float inv = 1.0f / (l_run*bA + lB*bBv);
#pragma unroll
    for(int r=0; r<16; r++){
      int rr = (r&3) + 8*(r>>2) + 4*hp;
      float bAr = __shfl(bA, rr);
      float invr = __shfl(inv, rr);
      int srow = brow0 + ws*32 + rr;
#pragma unroll
      for(int f=0; f<8; f++){
        float v = (acc[f][r]*bAr + mg[rr*256 + f*32 + l31]) * invr;
        Oc[(size_t)(b*Sz + srow)*DHh + h*Dm + f*32 + l31] = f2bf(v);
      }
    }
  }
}

// ---------------- output GEMM: out[4096x256] = concat[4096x2048] @ Wo + bo ---
// concat bf16, Wot bf16 [256][2048]; 4 warps, 64x64 tile, BK=64, double-buffered.
__global__ __launch_bounds__(256) void gemm_out(const unsigned short* __restrict__ A,
    const unsigned short* __restrict__ Bt, const float* __restrict__ bias,
    float* __restrict__ C){
  __shared__ __align__(16) char sm[32768];   // [db][A 8K | B 8K]
  const int tid = threadIdx.x, w = tid>>6, lane = tid&63, l31 = lane&31, hp = lane>>5;
  const int wm = (w>>1)*32, wn = (w&1)*32;
  const int bm = blockIdx.y*64, bn = blockIdx.x*64;
  f32x16 acc = z16();

  auto STAGE = [&](int db, int kk){
#pragma unroll
    for(int j=0; j<2; j++){
      int ci = (w*2+j)*64 + lane;          // 0..511
      int m = ci>>3, sl = ci&7;
      gll16(A  + (size_t)(bm+m)*DHh + kk + ((sl ^ (m&7))<<3), sm + db*16384 + (w*2+j)*1024);
      gll16(Bt + (size_t)(bn+m)*DHh + kk + ((sl ^ (m&7))<<3), sm + db*16384 + 8192 + (w*2+j)*1024);
    }
  };

  STAGE(0, 0);
  __syncthreads();
  int db = 0;
  for(int t=0; t<32; ++t){
    if(t<31) STAGE(db^1, (t+1)*64);
    const char* base = sm + db*16384;
#pragma unroll
    for(int s=0; s<4; s++){
      int m0 = wm + l31, n0 = wn + l31;
      short8 a = lds8(base + m0*128 + (((s*2+hp) ^ (m0&7))<<4));
      short8 b = lds8(base + 8192 + n0*128 + (((s*2+hp) ^ (n0&7))<<4));
      acc = MM(a, b, acc);
    }
    __syncthreads();
    db ^= 1;
  }
  float bb = bias[bn + wn + l31];
#pragma unroll
  for(int r=0; r<16; r++){
    int mrow = bm + wm + (r&3) + 8*(r>>2) + 4*hp;
    C[(size_t)mrow*Dm + bn + wn + l31] = acc[r] + bb;
  }
}

extern "C" void kernel_launch(void* const* d_in, const int* in_sizes, int n_in,
                              void* d_out, int out_size, void* d_ws, size_t ws_size,
                              hipStream_t stream){
  (void)in_sizes; (void)n_in; (void)out_size; (void)ws_size;
  const float* value_in = (const float*)d_in[0];
  const float* key_in   = (const float*)d_in[1];
  const float* query_in = (const float*)d_in[2];
  const float* Wv = (const float*)d_in[3];
  const float* bv = (const float*)d_in[4];
  const float* Wk = (const float*)d_in[5];
  const float* bk = (const float*)d_in[6];
  const float* Wq = (const float*)d_in[7];
  const float* bq = (const float*)d_in[8];
  const float* Wo = (const float*)d_in[9];
  const float* bo = (const float*)d_in[10];

  char* ws = (char*)d_ws;
  unsigned short* av  = (unsigned short*)(ws + ((size_t) 0u<<20));  // 2MB
  unsigned short* ak  = (unsigned short*)(ws + ((size_t) 2u<<20));  // 2MB
  unsigned short* aq  = (unsigned short*)(ws + ((size_t) 4u<<20));  // 2MB
  unsigned short* wtv = (unsigned short*)(ws + ((size_t) 6u<<20));  // 1MB
  unsigned short* wtk = (unsigned short*)(ws + ((size_t) 7u<<20));  // 1MB
  unsigned short* wtq = (unsigned short*)(ws + ((size_t) 8u<<20));  // 1MB
  unsigned short* wto = (unsigned short*)(ws + ((size_t) 9u<<20));  // 1MB
  unsigned short* vt  = (unsigned short*)(ws + ((size_t)10u<<20));  // 16MB [b][h][d][s]
  unsigned short* kb  = (unsigned short*)(ws + ((size_t)26u<<20));  // 16MB (pre-scaled)
  unsigned short* qb  = (unsigned short*)(ws + ((size_t)42u<<20));  // 16MB
  unsigned short* cc  = (unsigned short*)(ws + ((size_t)58u<<20));  // 16MB concat

  cvt_a<<<3072, 256, 0, stream>>>(value_in, key_in, query_in, av, ak, aq);
  cvt_w<<<dim3(64, 8, 4), 256, 0, stream>>>(Wv, Wk, Wq, Wo, wtv, wtk, wtq, wto);

  gemm_proj<2><<<dim3(16, 32), 256, 0, stream>>>(av, wtv, bv, vt);
  gemm_proj<1><<<dim3(16, 32), 256, 0, stream>>>(ak, wtk, bk, kb);
  gemm_proj<0><<<dim3(16, 32), 256, 0, stream>>>(aq, wtq, bq, qb);

  attn_mfma<<<256, 512, 0, stream>>>(kb, qb, vt, cc);

  gemm_out<<<dim3(4, 64), 256, 0, stream>>>(cc, wto, bo, (float*)d_out);
}